// Round 10
// baseline (65.550 us; speedup 1.0000x reference)
//
#include <hip/hip_runtime.h>

#define BB 8
#define HH 256
#define WW 256
#define NTOT (BB * HH * WW)   // 524288
#define RPB 4                 // rows per block in main kernel
#define NBLK (BB * HH / RPB)  // 512

// ---------------- Kernel 1: per-column foreground bitmasks (float4) --------
// Block = (stripe s, batch b): 32 rows x 256 cols. Thread t: column group
// c = t&63 (cols 4c..4c+3), row chunk rc = t>>6 (rows 8rc..8rc+7). Each
// thread does 8 float4 loads, packs 4x8 bits -> one u32 (byte per column),
// LDS-combines the 4 row-chunks, threads 0..63 store uint4 masks.
__global__ __launch_bounds__(256) void build_masks(
    const float* __restrict__ target, unsigned* __restrict__ masks) {
  __shared__ unsigned s_part[4][64];
  const int s = blockIdx.x;  // stripe 0..7
  const int b = blockIdx.y;  // batch 0..7
  const int t = threadIdx.x;
  const int c = t & 63;      // column group (4c..4c+3)
  const int rc = t >> 6;     // row chunk (8 rows)

  const float4* base = (const float4*)(target + b * (HH * WW) +
                                       (s * 32 + rc * 8) * WW) + c;
  unsigned pk = 0;  // byte c' = 8 row-bits for column 4c+c'
#pragma unroll
  for (int r = 0; r < 8; ++r) {
    const float4 v = base[r * (WW / 4)];
    if (v.x > 0.5f) pk |= (1u << r);
    if (v.y > 0.5f) pk |= (1u << (8 + r));
    if (v.z > 0.5f) pk |= (1u << (16 + r));
    if (v.w > 0.5f) pk |= (1u << (24 + r));
  }
  s_part[rc][c] = pk;
  __syncthreads();

  if (t < 64) {
    const unsigned p0 = s_part[0][t], p1 = s_part[1][t];
    const unsigned p2 = s_part[2][t], p3 = s_part[3][t];
    uint4 mo;
    mo.x = (p0 & 0xffu) | ((p1 & 0xffu) << 8) | ((p2 & 0xffu) << 16) |
           ((p3 & 0xffu) << 24);
    mo.y = ((p0 >> 8) & 0xffu) | (((p1 >> 8) & 0xffu) << 8) |
           (((p2 >> 8) & 0xffu) << 16) | (((p3 >> 8) & 0xffu) << 24);
    mo.z = ((p0 >> 16) & 0xffu) | (((p1 >> 16) & 0xffu) << 8) |
           (((p2 >> 16) & 0xffu) << 16) | (((p3 >> 16) & 0xffu) << 24);
    mo.w = (p0 >> 24) | ((p1 >> 24) << 8) | ((p2 >> 24) << 16) |
           ((p3 >> 24) << 24);
    ((uint4*)(masks + b * 2048 + s * 256))[t] = mo;
  }
}

// ------- Kernel 2: vertical EDT + pruned exact horizontal min + fused ------
// Block = RPB consecutive rows of one image. All 16 global loads (8 mask
// words + 4 logits + 4 target) are issued at kernel entry so their latency
// overlaps the mask/ctz math. Pruning exactness: k=j gives dt2(j) <= g2(j),
// so any argmin k* has |j-k*| <= d_j; R = block_max(min(d,255)) >= each
// row's own max -> exact. s_g2 has sentinel margins; +/-delta pairwise.
__global__ __launch_bounds__(256) void main_kernel(
    const float* __restrict__ logits, const float* __restrict__ target,
    const unsigned* __restrict__ masks,
    float* __restrict__ partials /* [5][NBLK] */) {
  __shared__ float s_g2[RPB][3 * WW];  // [pad | row | pad], sentinel-filled
  __shared__ float s_red[4 * 5];
  __shared__ int s_im[4 * 2];  // per-wave {any, rmax}

  const int g = blockIdx.x;        // 0..511
  const int b = g >> 6;            // 64 blocks per image
  const int i0 = (g & 63) * RPB;   // first row within image
  const int j = threadIdx.x;
  const int lane = j & 63, wave = j >> 6;

  // issue ALL global loads up front: masks, logits, target
  unsigned m[8];
#pragma unroll
  for (int w = 0; w < 8; ++w) m[w] = masks[b * 2048 + w * 256 + j];
  float xr[RPB], tr[RPB];
#pragma unroll
  for (int r = 0; r < RPB; ++r) {
    const int idx = (b * HH + i0 + r) * WW + j;
    xr[r] = logits[idx];
    tr[r] = target[idx];
  }
  const unsigned many = m[0] | m[1] | m[2] | m[3] | m[4] | m[5] | m[6] | m[7];

  // vertical distances for RPB rows; sentinel pads; track scan radius
  int rmax = 0;
#pragma unroll
  for (int r = 0; r < RPB; ++r) {
    const int i = i0 + r;
    const int wi = i >> 5, rr = i & 31;
    int dUp = 1 << 30, dDn = 1 << 30;
    const unsigned cur = m[wi] >> rr;  // bits at rows >= i
    if (cur) {
      dUp = __builtin_ctz(cur);
    } else {
      int off = 32 - rr;
      for (int w2 = wi + 1; w2 < 8; ++w2, off += 32)
        if (m[w2]) { dUp = off + __builtin_ctz(m[w2]); break; }
    }
    const unsigned curd = m[wi] << (31 - rr);  // bits at rows <= i
    if (curd) {
      dDn = __builtin_clz(curd);
    } else {
      int off = rr + 1;
      for (int w2 = wi - 1; w2 >= 0; --w2, off += 32)
        if (m[w2]) { dDn = off + __builtin_clz(m[w2]); break; }
    }
    const int d = min(dUp, dDn);
    s_g2[r][WW + j] = (d < 256) ? (float)(d * d) : 1.0e9f;
    s_g2[r][j] = 1.0e9f;           // left pad
    s_g2[r][2 * WW + j] = 1.0e9f;  // right pad
    rmax = max(rmax, min(d, 255));
  }

  const int wave_any = __any(many != 0u);
#pragma unroll
  for (int off = 32; off > 0; off >>= 1)
    rmax = max(rmax, __shfl_down(rmax, off, 64));
  if (lane == 0) { s_im[wave * 2] = wave_any; s_im[wave * 2 + 1] = rmax; }
  __syncthreads();
  const int nonempty = s_im[0] | s_im[2] | s_im[4] | s_im[6];
  const int R = max(max(s_im[1], s_im[3]), max(s_im[5], s_im[7]));

  // per-row pruned horizontal min + fused elementwise, accumulated locally
  float v0 = 0.f, v1 = 0.f, v2 = 0.f, v3 = 0.f, v4 = 0.f;
#pragma unroll
  for (int r = 0; r < RPB; ++r) {
    const float* gp = &s_g2[r][WW + j];
    float mn = gp[0];
    for (int dlt = 1; dlt <= R; ++dlt) {
      const float d2 = (float)(dlt * dlt);
      mn = fminf(mn, fminf(d2 + gp[dlt], d2 + gp[-dlt]));
    }
    const float dt = nonempty ? sqrtf(mn) : 0.0f;

    const float x = xr[r];
    float t = fminf(fmaxf(tr[r], 0.0f), 1.0f);
    const float e = __expf(-fabsf(x));
    const float inv = 1.0f / (1.0f + e);
    const float ce = fmaxf(x, 0.0f) + __logf(1.0f + e) - x * t;
    float p = (x >= 0.0f) ? inv : e * inv;  // sigmoid
    p = fminf(fmaxf(p, 1e-6f), 1.0f - 1e-6f);
    v0 += ce; v1 += p; v2 += t; v3 += p * t; v4 += p * dt;
  }

  // block reduce (fp32) -> plain per-block partial stores
  float v[5] = {v0, v1, v2, v3, v4};
#pragma unroll
  for (int q = 0; q < 5; ++q) {
    float s = v[q];
#pragma unroll
    for (int off = 32; off > 0; off >>= 1) s += __shfl_down(s, off, 64);
    if (lane == 0) s_red[wave * 5 + q] = s;
  }
  __syncthreads();
  if (j == 0) {
#pragma unroll
    for (int q = 0; q < 5; ++q)
      partials[q * NBLK + g] =
          s_red[q] + s_red[5 + q] + s_red[10 + q] + s_red[15 + q];
  }
}

// ---------------- Kernel 3: final reduction (double) + loss math -----------
__global__ __launch_bounds__(256) void finalize(
    const float* __restrict__ partials, float* __restrict__ out) {
  __shared__ double s_red[4 * 5];
  const int j = threadIdx.x;  // 256 threads
  const int lane = j & 63, wave = j >> 6;
  double acc[5];
#pragma unroll
  for (int q = 0; q < 5; ++q)
    acc[q] = (double)partials[q * NBLK + j] +
             (double)partials[q * NBLK + 256 + j];
#pragma unroll
  for (int q = 0; q < 5; ++q) {
    double s = acc[q];
#pragma unroll
    for (int off = 32; off > 0; off >>= 1) s += __shfl_down(s, off, 64);
    if (lane == 0) s_red[wave * 5 + q] = s;
  }
  __syncthreads();
  if (j == 0) {
    double sum[5];
#pragma unroll
    for (int q = 0; q < 5; ++q)
      sum[q] = s_red[q] + s_red[5 + q] + s_red[10 + q] + s_red[15 + q];
    const double n = (double)NTOT;
    const double ce = sum[0] / n;
    const double dice = 1.0 - (2.0 * sum[3] + 1e-6) / (sum[1] + sum[2] + 1e-6);
    const double boundary = sum[4] / n;
    out[0] = (float)(ce + dice + 0.1 * boundary);
    out[1] = (float)ce;
    out[2] = (float)dice;
    out[3] = (float)boundary;
  }
}

extern "C" void kernel_launch(void* const* d_in, const int* in_sizes, int n_in,
                              void* d_out, int out_size, void* d_ws,
                              size_t ws_size, hipStream_t stream) {
  const float* logits = (const float*)d_in[0];
  const float* target = (const float*)d_in[1];
  float* out = (float*)d_out;

  char* ws = (char*)d_ws;
  unsigned* masks = (unsigned*)ws;              // 8*2048*4 = 64 KB
  float* partials = (float*)(ws + 64 * 1024);   // 5*512*4 = 10 KB

  build_masks<<<dim3(8, 8), 256, 0, stream>>>(target, masks);
  main_kernel<<<NBLK, 256, 0, stream>>>(logits, target, masks, partials);
  finalize<<<1, 256, 0, stream>>>(partials, out);
}